// Round 1
// baseline (188.516 us; speedup 1.0000x reference)
//
#include <hip/hip_runtime.h>

#define LOG2E_2 2.8853900817779268f  // 2*log2(e)

__device__ __forceinline__ float fexp2(float x){ return __builtin_amdgcn_exp2f(x); }
__device__ __forceinline__ float frcp (float x){ return __builtin_amdgcn_rcpf(x); }

// tanh(v) = 1 - 2/(1+exp(2v))
__device__ __forceinline__ float ftanh(float v){
    return 1.0f - 2.0f * frcp(1.0f + fexp2(LOG2E_2 * v));
}

// K1: hv[1024][1024] = tanh( x @ [W_foh | W_fom] + catBias ), x = [lstms0|lstms1], K=512
__global__ __launch_bounds__(256) void k1_gemm_tanh(
    const float* __restrict__ l0, const float* __restrict__ l1,
    const float* __restrict__ Wfoh, const float* __restrict__ Wfom,
    const float* __restrict__ cb, float* __restrict__ hv)
{
    __shared__ float As[16][68];   // [k][m], pad 68: ty-stride 272w -> 2-way (free)
    __shared__ float Bs[16][68];   // [k][n]
    const int tid = threadIdx.x;
    const int tx = tid & 15, ty = tid >> 4;
    const int bx = blockIdx.x, by = blockIdx.y;
    const int c0 = bx * 64;
    const float* W = (c0 < 512) ? (Wfoh + c0) : (Wfom + (c0 - 512));

    const int lrow = tid >> 2;          // 0..63
    const int lkk  = (tid & 3) * 4;     // 0,4,8,12
    const int bk   = tid >> 4;          // 0..15
    const int bn   = (tid & 15) * 4;    // 0..60

    float acc[4][4] = {};

    for (int k0 = 0; k0 < 512; k0 += 16) {
        int gk = k0 + lkk;
        const float* asrc = (gk < 256) ? (l0 + (by*64 + lrow)*256 + gk)
                                       : (l1 + (by*64 + lrow)*256 + (gk - 256));
        float4 av = *(const float4*)asrc;
        As[lkk+0][lrow] = av.x;
        As[lkk+1][lrow] = av.y;
        As[lkk+2][lrow] = av.z;
        As[lkk+3][lrow] = av.w;
        float4 bv = *(const float4*)(W + (k0 + bk)*512 + bn);
        *(float4*)&Bs[bk][bn] = bv;
        __syncthreads();
        #pragma unroll
        for (int k = 0; k < 16; ++k) {
            float4 a = *(const float4*)&As[k][ty*4];
            float4 b = *(const float4*)&Bs[k][tx*4];
            float a4[4] = {a.x, a.y, a.z, a.w};
            float b4[4] = {b.x, b.y, b.z, b.w};
            #pragma unroll
            for (int r = 0; r < 4; ++r)
                #pragma unroll
                for (int q = 0; q < 4; ++q)
                    acc[r][q] = fmaf(a4[r], b4[q], acc[r][q]);
        }
        __syncthreads();
    }

    const int row0 = by*64 + ty*4;
    const int col0 = c0 + tx*4;
    #pragma unroll
    for (int r = 0; r < 4; ++r) {
        float4 o;
        o.x = ftanh(acc[r][0] + cb[col0+0]);
        o.y = ftanh(acc[r][1] + cb[col0+1]);
        o.z = ftanh(acc[r][2] + cb[col0+2]);
        o.w = ftanh(acc[r][3] + cb[col0+3]);
        *(float4*)&hv[(row0+r)*1024 + col0] = o;
    }
}

// K2: P[1024][512]: cols 0..255 = a2 = c*(ah@W2[:512] + h2b); cols 256..511 = b2 = c*(am@W2[512:])
__global__ __launch_bounds__(256) void k2_gemm(
    const float* __restrict__ hv, const float* __restrict__ W2,
    const float* __restrict__ h2b, float* __restrict__ P)
{
    __shared__ float As[16][68];
    __shared__ float Bs[16][68];
    const int tid = threadIdx.x;
    const int tx = tid & 15, ty = tid >> 4;
    const int bx = blockIdx.x, by = blockIdx.y;
    const int c0 = bx * 64;                 // output col t base (0..448)
    const int half = (c0 >= 256) ? 1 : 0;
    const int ho = half ? 512 : 0;          // offset into hv cols and W2 rows
    const int tc0 = c0 - (half ? 256 : 0);  // col within W2

    const int lrow = tid >> 2;
    const int lkk  = (tid & 3) * 4;
    const int bk   = tid >> 4;
    const int bn   = (tid & 15) * 4;

    float acc[4][4] = {};

    for (int k0 = 0; k0 < 512; k0 += 16) {
        float4 av = *(const float4*)(hv + (by*64 + lrow)*1024 + ho + k0 + lkk);
        As[lkk+0][lrow] = av.x;
        As[lkk+1][lrow] = av.y;
        As[lkk+2][lrow] = av.z;
        As[lkk+3][lrow] = av.w;
        float4 bv = *(const float4*)(W2 + (ho + k0 + bk)*256 + tc0 + bn);
        *(float4*)&Bs[bk][bn] = bv;
        __syncthreads();
        #pragma unroll
        for (int k = 0; k < 16; ++k) {
            float4 a = *(const float4*)&As[k][ty*4];
            float4 b = *(const float4*)&Bs[k][tx*4];
            float a4[4] = {a.x, a.y, a.z, a.w};
            float b4[4] = {b.x, b.y, b.z, b.w};
            #pragma unroll
            for (int r = 0; r < 4; ++r)
                #pragma unroll
                for (int q = 0; q < 4; ++q)
                    acc[r][q] = fmaf(a4[r], b4[q], acc[r][q]);
        }
        __syncthreads();
    }

    const int row0 = by*64 + ty*4;
    const int col0 = c0 + tx*4;
    #pragma unroll
    for (int r = 0; r < 4; ++r) {
        float4 o;
        float b0 = half ? 0.0f : h2b[col0+0];
        float b1 = half ? 0.0f : h2b[col0+1];
        float b2v = half ? 0.0f : h2b[col0+2];
        float b3 = half ? 0.0f : h2b[col0+3];
        o.x = (acc[r][0] + b0) * LOG2E_2;
        o.y = (acc[r][1] + b1) * LOG2E_2;
        o.z = (acc[r][2] + b2v) * LOG2E_2;
        o.w = (acc[r][3] + b3) * LOG2E_2;
        *(float4*)&P[(row0+r)*512 + col0] = o;
    }
}

// K3: score[i,j] = ob + sum_h w[h]*tanh(A'[i,h]+B[j,h])
//               = ob + sumw - 2*sum_h w[h]*rcp(1+exp2(a2[i,h]+b2[j,h]))
// 64x64 score tile per block, 512 threads (8 waves -> 2/SIMD), 4x(64-h) chunks.
__global__ __launch_bounds__(512) void k3_pairwise(
    const float* __restrict__ P, const float* __restrict__ w,
    const float* __restrict__ ob, float* __restrict__ out)
{
    __shared__ float As[64][68];   // a2 chunk: [i][hh]
    __shared__ float Bs[64][68];   // b2 chunk transposed: [hh][j]
    __shared__ float wls[256];
    const int tid = threadIdx.x;
    const int tx = tid & 15;       // j-group: cols tx*4..tx*4+3
    const int ty = tid >> 4;       // 0..31: rows ty*2, ty*2+1
    const int i0 = blockIdx.y * 64, j0 = blockIdx.x * 64;

    if (tid < 256) wls[tid] = w[tid];

    float acc[2][4] = {};
    float sumw = 0.0f;

    for (int h0 = 0; h0 < 256; h0 += 64) {
        __syncthreads();
        #pragma unroll
        for (int it = 0; it < 2; ++it) {
            int idx = tid + it*512;      // 0..1023
            int rr  = idx >> 4;          // 0..63
            int c4  = (idx & 15) * 4;    // 0..60
            float4 av = *(const float4*)&P[(i0+rr)*512 + h0 + c4];
            *(float4*)&As[rr][c4] = av;
            float4 bv = *(const float4*)&P[(j0+rr)*512 + 256 + h0 + c4];
            Bs[c4+0][rr] = bv.x;
            Bs[c4+1][rr] = bv.y;
            Bs[c4+2][rr] = bv.z;
            Bs[c4+3][rr] = bv.w;
        }
        __syncthreads();

        for (int hh = 0; hh < 64; hh += 4) {
            float4 wv = *(const float4*)&wls[h0 + hh];
            sumw += wv.x + wv.y + wv.z + wv.w;
            float4 a0 = *(const float4*)&As[ty*2+0][hh];
            float4 a1 = *(const float4*)&As[ty*2+1][hh];
            float4 bq0 = *(const float4*)&Bs[hh+0][tx*4];
            float4 bq1 = *(const float4*)&Bs[hh+1][tx*4];
            float4 bq2 = *(const float4*)&Bs[hh+2][tx*4];
            float4 bq3 = *(const float4*)&Bs[hh+3][tx*4];
            float aa[2][4] = {{a0.x,a0.y,a0.z,a0.w},{a1.x,a1.y,a1.z,a1.w}};
            float bb[4][4] = {{bq0.x,bq0.y,bq0.z,bq0.w},
                              {bq1.x,bq1.y,bq1.z,bq1.w},
                              {bq2.x,bq2.y,bq2.z,bq2.w},
                              {bq3.x,bq3.y,bq3.z,bq3.w}};
            float ww[4] = {wv.x, wv.y, wv.z, wv.w};
            #pragma unroll
            for (int h = 0; h < 4; ++h)
                #pragma unroll
                for (int r = 0; r < 2; ++r)
                    #pragma unroll
                    for (int q = 0; q < 4; ++q) {
                        float s  = aa[r][h] + bb[h][q];
                        float rr = frcp(1.0f + fexp2(s));
                        acc[r][q] = fmaf(ww[h], rr, acc[r][q]);
                    }
        }
    }

    const float base = ob[0] + sumw;
    const int row = i0 + ty*2;
    const int col = j0 + tx*4;
    #pragma unroll
    for (int r = 0; r < 2; ++r) {
        float4 o;
        o.x = base - 2.0f*acc[r][0];
        o.y = base - 2.0f*acc[r][1];
        o.z = base - 2.0f*acc[r][2];
        o.w = base - 2.0f*acc[r][3];
        *(float4*)&out[(row+r)*1024 + col] = o;
    }
}

extern "C" void kernel_launch(void* const* d_in, const int* in_sizes, int n_in,
                              void* d_out, int out_size, void* d_ws, size_t ws_size,
                              hipStream_t stream) {
    const float* l0   = (const float*)d_in[0];  // lstms0 [1024,256]
    const float* l1   = (const float*)d_in[1];  // lstms1 [1024,256]
    const float* Wfoh = (const float*)d_in[2];  // [512,512]
    const float* Wfom = (const float*)d_in[3];  // [512,512]
    const float* cb   = (const float*)d_in[4];  // [1024]
    const float* W2   = (const float*)d_in[5];  // [1024,256]
    const float* h2b  = (const float*)d_in[6];  // [256]
    const float* w    = (const float*)d_in[7];  // [256]
    const float* ob   = (const float*)d_in[8];  // [1]
    float* out = (float*)d_out;                 // [1024,1024]

    float* hv = (float*)d_ws;                   // [1024,1024] = 4 MB
    float* P  = hv + 1024*1024;                 // [1024,512]  = 2 MB

    k1_gemm_tanh<<<dim3(16,16), 256, 0, stream>>>(l0, l1, Wfoh, Wfom, cb, hv);
    k2_gemm     <<<dim3(8,16),  256, 0, stream>>>(hv, W2, h2b, P);
    k3_pairwise <<<dim3(16,16), 512, 0, stream>>>(P, w, ob, out);
}

// Round 2
// 165.574 us; speedup vs baseline: 1.1386x; 1.1386x over previous
//
#include <hip/hip_runtime.h>

#define LOG2E_2 2.8853900817779268f  // 2*log2(e)

__device__ __forceinline__ float fexp2(float x){ return __builtin_amdgcn_exp2f(x); }
__device__ __forceinline__ float frcp (float x){ return __builtin_amdgcn_rcpf(x); }

// tanh(v) = 1 - 2/(1+exp(2v))
__device__ __forceinline__ float ftanh(float v){
    return 1.0f - 2.0f * frcp(1.0f + fexp2(LOG2E_2 * v));
}

// K1: hv[1024][1024] = tanh( x @ [W_foh | W_fom] + catBias ), x = [lstms0|lstms1], K=512
// 64x64 tile, 512 threads (8 waves, 2/SIMD), BK=32, reg-prefetch pipeline.
__global__ __launch_bounds__(512) void k1_gemm_tanh(
    const float* __restrict__ l0, const float* __restrict__ l1,
    const float* __restrict__ Wfoh, const float* __restrict__ Wfom,
    const float* __restrict__ cb, float* __restrict__ hv)
{
    __shared__ float As[32][68];   // [k][m]
    __shared__ float Bs[32][68];   // [k][n]
    const int tid = threadIdx.x;
    const int tx = tid & 15, ty = tid >> 4;       // ty 0..31
    const int bx = blockIdx.x, by = blockIdx.y;
    const int c0 = bx * 64;
    const float* W = (c0 < 512) ? (Wfoh + c0) : (Wfom + (c0 - 512));

    // staging indices: every thread 1 A-float4 + 1 B-float4 per chunk
    const int lrow = tid >> 3;          // 0..63
    const int lkk  = (tid & 7) * 4;     // 0..28
    const int bk   = tid >> 4;          // 0..31
    const int bn   = (tid & 15) * 4;    // 0..60

    const int arow = by*64 + lrow;

    float acc[2][4] = {};

    // prefetch chunk 0
    int gk = 0 + lkk;
    float4 aReg = (gk < 256) ? *(const float4*)(l0 + arow*256 + gk)
                             : *(const float4*)(l1 + arow*256 + gk - 256);
    float4 bReg = *(const float4*)(W + (0 + bk)*512 + bn);

    for (int c = 0; c < 16; ++c) {
        __syncthreads();
        As[lkk+0][lrow] = aReg.x;
        As[lkk+1][lrow] = aReg.y;
        As[lkk+2][lrow] = aReg.z;
        As[lkk+3][lrow] = aReg.w;
        *(float4*)&Bs[bk][bn] = bReg;
        __syncthreads();
        if (c + 1 < 16) {
            int k0 = (c+1) * 32;
            gk = k0 + lkk;
            aReg = (gk < 256) ? *(const float4*)(l0 + arow*256 + gk)
                              : *(const float4*)(l1 + arow*256 + gk - 256);
            bReg = *(const float4*)(W + (k0 + bk)*512 + bn);
        }
        #pragma unroll
        for (int k = 0; k < 32; ++k) {
            float2 a = *(const float2*)&As[k][ty*2];
            float4 b = *(const float4*)&Bs[k][tx*4];
            float a2v[2] = {a.x, a.y};
            float b4[4] = {b.x, b.y, b.z, b.w};
            #pragma unroll
            for (int r = 0; r < 2; ++r)
                #pragma unroll
                for (int q = 0; q < 4; ++q)
                    acc[r][q] = fmaf(a2v[r], b4[q], acc[r][q]);
        }
    }

    const int row0 = by*64 + ty*2;
    const int col0 = c0 + tx*4;
    #pragma unroll
    for (int r = 0; r < 2; ++r) {
        float4 o;
        o.x = ftanh(acc[r][0] + cb[col0+0]);
        o.y = ftanh(acc[r][1] + cb[col0+1]);
        o.z = ftanh(acc[r][2] + cb[col0+2]);
        o.w = ftanh(acc[r][3] + cb[col0+3]);
        *(float4*)&hv[(row0+r)*1024 + col0] = o;
    }
}

// K2: P[1024][512]: cols 0..255 = a2 = c*(ah@W2[:512] + h2b); cols 256..511 = b2 = c*(am@W2[512:])
// 32x64 tile, grid (8,32)=256 blocks, 512 threads, BK=32, reg-prefetch pipeline.
__global__ __launch_bounds__(512) void k2_gemm(
    const float* __restrict__ hv, const float* __restrict__ W2,
    const float* __restrict__ h2b, float* __restrict__ P)
{
    __shared__ float As[32][36];   // [k][m], m=0..31
    __shared__ float Bs[32][68];   // [k][n]
    const int tid = threadIdx.x;
    const int tx = tid & 15, ty = tid >> 4;       // ty 0..31 = output row
    const int bx = blockIdx.x, by = blockIdx.y;
    const int c0 = bx * 64;
    const int half = (c0 >= 256) ? 1 : 0;
    const int ho = half ? 512 : 0;
    const int tc0 = c0 - (half ? 256 : 0);

    const int lrow = tid >> 3;          // 0..63 (use <32)
    const int lkk  = (tid & 7) * 4;
    const int bk   = tid >> 4;          // 0..31
    const int bn   = (tid & 15) * 4;

    float acc[4] = {};

    float4 aReg = {};
    if (tid < 256)
        aReg = *(const float4*)(hv + (by*32 + lrow)*1024 + ho + 0 + lkk);
    float4 bReg = *(const float4*)(W2 + (ho + 0 + bk)*256 + tc0 + bn);

    for (int c = 0; c < 16; ++c) {
        __syncthreads();
        if (tid < 256) {
            As[lkk+0][lrow] = aReg.x;
            As[lkk+1][lrow] = aReg.y;
            As[lkk+2][lrow] = aReg.z;
            As[lkk+3][lrow] = aReg.w;
        }
        *(float4*)&Bs[bk][bn] = bReg;
        __syncthreads();
        if (c + 1 < 16) {
            int k0 = (c+1) * 32;
            if (tid < 256)
                aReg = *(const float4*)(hv + (by*32 + lrow)*1024 + ho + k0 + lkk);
            bReg = *(const float4*)(W2 + (ho + k0 + bk)*256 + tc0 + bn);
        }
        #pragma unroll
        for (int k = 0; k < 32; ++k) {
            float a = As[k][ty];
            float4 b = *(const float4*)&Bs[k][tx*4];
            acc[0] = fmaf(a, b.x, acc[0]);
            acc[1] = fmaf(a, b.y, acc[1]);
            acc[2] = fmaf(a, b.z, acc[2]);
            acc[3] = fmaf(a, b.w, acc[3]);
        }
    }

    const int row = by*32 + ty;
    const int col0 = c0 + tx*4;
    float4 o;
    float b0 = half ? 0.0f : h2b[col0+0];
    float b1 = half ? 0.0f : h2b[col0+1];
    float b2v = half ? 0.0f : h2b[col0+2];
    float b3 = half ? 0.0f : h2b[col0+3];
    o.x = (acc[0] + b0) * LOG2E_2;
    o.y = (acc[1] + b1) * LOG2E_2;
    o.z = (acc[2] + b2v) * LOG2E_2;
    o.w = (acc[3] + b3) * LOG2E_2;
    *(float4*)&P[row*512 + col0] = o;
}

// K3: score[i,j] = ob + sumw - 2*sum_h w[h]*rcp(1+exp2(a2[i,h]+b2[j,h]))
// 32x32 score tile, grid 32x32 = 1024 blocks, 256 threads -> 4 blocks/CU, 16 waves/CU.
__global__ __launch_bounds__(256) void k3_pairwise(
    const float* __restrict__ P, const float* __restrict__ w,
    const float* __restrict__ ob, float* __restrict__ out)
{
    __shared__ float As[32][68];   // a2 chunk: [i][hh]
    __shared__ float Bs[64][34];   // b2 chunk transposed: [hh][j]
    __shared__ float wls[256];
    const int tid = threadIdx.x;
    const int tx = tid & 15;       // j-group: cols tx*2..tx*2+1
    const int ty = tid >> 4;       // 0..15: rows ty*2, ty*2+1
    const int i0 = blockIdx.y * 32, j0 = blockIdx.x * 32;

    wls[tid] = w[tid];

    float acc[2][2] = {};
    float sumw = 0.0f;

    for (int h0 = 0; h0 < 256; h0 += 64) {
        __syncthreads();
        #pragma unroll
        for (int it = 0; it < 2; ++it) {
            int idx = tid + it*256;      // 0..511
            int rr  = idx >> 4;          // 0..31
            int c4  = (idx & 15) * 4;    // 0..60
            float4 av = *(const float4*)&P[(i0+rr)*512 + h0 + c4];
            *(float4*)&As[rr][c4] = av;
            float4 bv = *(const float4*)&P[(j0+rr)*512 + 256 + h0 + c4];
            Bs[c4+0][rr] = bv.x;
            Bs[c4+1][rr] = bv.y;
            Bs[c4+2][rr] = bv.z;
            Bs[c4+3][rr] = bv.w;
        }
        __syncthreads();

        for (int hh = 0; hh < 64; hh += 4) {
            float4 wv = *(const float4*)&wls[h0 + hh];
            sumw += wv.x + wv.y + wv.z + wv.w;
            float4 a0 = *(const float4*)&As[ty*2+0][hh];
            float4 a1 = *(const float4*)&As[ty*2+1][hh];
            float2 bq0 = *(const float2*)&Bs[hh+0][tx*2];
            float2 bq1 = *(const float2*)&Bs[hh+1][tx*2];
            float2 bq2 = *(const float2*)&Bs[hh+2][tx*2];
            float2 bq3 = *(const float2*)&Bs[hh+3][tx*2];
            float aa[2][4] = {{a0.x,a0.y,a0.z,a0.w},{a1.x,a1.y,a1.z,a1.w}};
            float bb[4][2] = {{bq0.x,bq0.y},{bq1.x,bq1.y},{bq2.x,bq2.y},{bq3.x,bq3.y}};
            float ww[4] = {wv.x, wv.y, wv.z, wv.w};
            #pragma unroll
            for (int h = 0; h < 4; ++h)
                #pragma unroll
                for (int r = 0; r < 2; ++r)
                    #pragma unroll
                    for (int q = 0; q < 2; ++q) {
                        float s  = aa[r][h] + bb[h][q];
                        float rr = frcp(1.0f + fexp2(s));
                        acc[r][q] = fmaf(ww[h], rr, acc[r][q]);
                    }
        }
    }

    const float base = ob[0] + sumw;
    const int row = i0 + ty*2;
    const int col = j0 + tx*2;
    #pragma unroll
    for (int r = 0; r < 2; ++r) {
        float2 o;
        o.x = base - 2.0f*acc[r][0];
        o.y = base - 2.0f*acc[r][1];
        *(float2*)&out[(row+r)*1024 + col] = o;
    }
}

extern "C" void kernel_launch(void* const* d_in, const int* in_sizes, int n_in,
                              void* d_out, int out_size, void* d_ws, size_t ws_size,
                              hipStream_t stream) {
    const float* l0   = (const float*)d_in[0];  // lstms0 [1024,256]
    const float* l1   = (const float*)d_in[1];  // lstms1 [1024,256]
    const float* Wfoh = (const float*)d_in[2];  // [512,512]
    const float* Wfom = (const float*)d_in[3];  // [512,512]
    const float* cb   = (const float*)d_in[4];  // [1024]
    const float* W2   = (const float*)d_in[5];  // [1024,256]
    const float* h2b  = (const float*)d_in[6];  // [256]
    const float* w    = (const float*)d_in[7];  // [256]
    const float* ob   = (const float*)d_in[8];  // [1]
    float* out = (float*)d_out;                 // [1024,1024]

    float* hv = (float*)d_ws;                   // [1024,1024] = 4 MB
    float* P  = hv + 1024*1024;                 // [1024,512]  = 2 MB

    k1_gemm_tanh<<<dim3(16,16), 512, 0, stream>>>(l0, l1, Wfoh, Wfom, cb, hv);
    k2_gemm     <<<dim3(8,32),  512, 0, stream>>>(hv, W2, h2b, P);
    k3_pairwise <<<dim3(32,32), 256, 0, stream>>>(P, w, ob, out);
}

// Round 3
// 135.230 us; speedup vs baseline: 1.3940x; 1.2244x over previous
//
#include <hip/hip_runtime.h>
#include <hip/hip_bf16.h>

typedef short s16x4 __attribute__((ext_vector_type(4)));
typedef float f32x4 __attribute__((ext_vector_type(4)));

#define LOG2E_2 2.8853900817779268f  // 2*log2(e)

__device__ __forceinline__ float fexp2(float x){ return __builtin_amdgcn_exp2f(x); }
__device__ __forceinline__ float frcp (float x){ return __builtin_amdgcn_rcpf(x); }
// tanh(v) = 1 - 2/(1+exp(2v)) = 1 - 2*rcp(1+exp2(LOG2E_2*v))
__device__ __forceinline__ float ftanh(float v){
    return 1.0f - 2.0f * frcp(1.0f + fexp2(LOG2E_2 * v));
}
__device__ __forceinline__ unsigned short f2bf(float v){
    __hip_bfloat16 h = __float2bfloat16(v);
    return __builtin_bit_cast(unsigned short, h);
}
__device__ __forceinline__ float bf2f(unsigned short u){
    return __bfloat162float(__builtin_bit_cast(__hip_bfloat16, u));
}
__device__ __forceinline__ f32x4 mfma_bf16(s16x4 a, s16x4 b, f32x4 c){
    return __builtin_amdgcn_mfma_f32_16x16x16bf16_1k(a, b, c, 0, 0, 0);
}

// ---------- prep: x = [l0|l1] -> bf16 hi/lo, row-major [1024][512] ----------
__global__ __launch_bounds__(256) void prep_x(
    const float* __restrict__ l0, const float* __restrict__ l1,
    unsigned short* __restrict__ xhi, unsigned short* __restrict__ xlo)
{
    int idx = (blockIdx.x * 256 + threadIdx.x) * 4;   // grid 512 -> covers 512K elems
    int r = idx >> 9, c = idx & 511;
    float4 v = (c < 256) ? *(const float4*)(l0 + r*256 + c)
                         : *(const float4*)(l1 + r*256 + (c - 256));
    ushort4 h, l;
    h.x = f2bf(v.x); l.x = f2bf(v.x - bf2f(h.x));
    h.y = f2bf(v.y); l.y = f2bf(v.y - bf2f(h.y));
    h.z = f2bf(v.z); l.z = f2bf(v.z - bf2f(h.z));
    h.w = f2bf(v.w); l.w = f2bf(v.w - bf2f(h.w));
    *(ushort4*)(xhi + idx) = h;
    *(ushort4*)(xlo + idx) = l;
}

// ---------- prep: transpose+split W[k][n] (fp32) -> Wt_hi/lo[n][k] (bf16) ----------
// src(k,n) = n < splitN ? srcA[k*lda+n] : srcB[k*lda+n-splitN]
__global__ __launch_bounds__(256) void prep_wt(
    const float* __restrict__ srcA, const float* __restrict__ srcB,
    int splitN, int lda, int K,
    unsigned short* __restrict__ dhi, unsigned short* __restrict__ dlo)
{
    __shared__ float F[32][33];
    const int t = threadIdx.x;
    const int k0 = blockIdx.x * 32, n0 = blockIdx.y * 32;
    {
        int kk = t >> 3, n4 = (t & 7) * 4;
        int n = n0 + n4;
        const float* s = (n < splitN) ? (srcA + (k0+kk)*lda + n)
                                      : (srcB + (k0+kk)*lda + (n - splitN));
        float4 v = *(const float4*)s;
        F[kk][n4+0] = v.x; F[kk][n4+1] = v.y; F[kk][n4+2] = v.z; F[kk][n4+3] = v.w;
    }
    __syncthreads();
    {
        int nn = t >> 3, k4 = (t & 7) * 4;
        ushort4 h, l;
        float v0 = F[k4+0][nn]; h.x = f2bf(v0); l.x = f2bf(v0 - bf2f(h.x));
        float v1 = F[k4+1][nn]; h.y = f2bf(v1); l.y = f2bf(v1 - bf2f(h.y));
        float v2 = F[k4+2][nn]; h.z = f2bf(v2); l.z = f2bf(v2 - bf2f(h.z));
        float v3 = F[k4+3][nn]; h.w = f2bf(v3); l.w = f2bf(v3 - bf2f(h.w));
        *(ushort4*)(dhi + (n0+nn)*K + k0 + k4) = h;
        *(ushort4*)(dlo + (n0+nn)*K + k0 + k4) = l;
    }
}

// ---------- K1: hv = tanh(x @ [Wfoh|Wfom] + cb), split-bf16 MFMA ----------
// M=1024,N=1024,K=512. Tile 64(m)x32(n), grid (32,16)=512 blocks, 256 thr (4 waves).
// Wave w: m-strip w*16, both 16-col n-tiles. Output as bf16 hi/lo for K2.
__global__ __launch_bounds__(256) void k1_mfma(
    const unsigned short* __restrict__ xhi, const unsigned short* __restrict__ xlo,
    const unsigned short* __restrict__ whi, const unsigned short* __restrict__ wlo,
    const float* __restrict__ cb,
    unsigned short* __restrict__ hvhi, unsigned short* __restrict__ hvlo)
{
    __shared__ unsigned short Ah[64][40], Al[64][40], Bh[32][40], Bl[32][40]; // pad 40: 80B rows
    const int t = threadIdx.x;
    const int r0 = blockIdx.y * 64, c0 = blockIdx.x * 32;
    const int w = t >> 6, lane = t & 63;
    const int m = lane & 15, quad = lane >> 4;

    const int arow = t >> 2, aseg = t & 3;          // 256 A slots (64 rows x 4 k-segs of 8)
    const int brow = (t & 127) >> 2, bseg = t & 3;  // 128 B slots (t<128)
    const bool doB = (t < 128);

    f32x4 acc0 = {0,0,0,0}, acc1 = {0,0,0,0};

    uint4 pah = *(const uint4*)(xhi + (r0+arow)*512 + aseg*8);
    uint4 pal = *(const uint4*)(xlo + (r0+arow)*512 + aseg*8);
    uint4 pbh = {}, pbl = {};
    if (doB) {
        pbh = *(const uint4*)(whi + (c0+brow)*512 + bseg*8);
        pbl = *(const uint4*)(wlo + (c0+brow)*512 + bseg*8);
    }

    for (int c = 0; c < 16; ++c) {
        __syncthreads();
        *(uint4*)&Ah[arow][aseg*8] = pah;
        *(uint4*)&Al[arow][aseg*8] = pal;
        if (doB) {
            *(uint4*)&Bh[brow][bseg*8] = pbh;
            *(uint4*)&Bl[brow][bseg*8] = pbl;
        }
        __syncthreads();
        if (c + 1 < 16) {
            int k0 = (c+1) * 32;
            pah = *(const uint4*)(xhi + (r0+arow)*512 + k0 + aseg*8);
            pal = *(const uint4*)(xlo + (r0+arow)*512 + k0 + aseg*8);
            if (doB) {
                pbh = *(const uint4*)(whi + (c0+brow)*512 + k0 + bseg*8);
                pbl = *(const uint4*)(wlo + (c0+brow)*512 + k0 + bseg*8);
            }
        }
        #pragma unroll
        for (int ks = 0; ks < 32; ks += 16) {
            const int ko = ks + quad*4;
            s16x4 ah = *(const s16x4*)&Ah[w*16 + m][ko];
            s16x4 al = *(const s16x4*)&Al[w*16 + m][ko];
            s16x4 b0h = *(const s16x4*)&Bh[m][ko];
            s16x4 b0l = *(const s16x4*)&Bl[m][ko];
            s16x4 b1h = *(const s16x4*)&Bh[16 + m][ko];
            s16x4 b1l = *(const s16x4*)&Bl[16 + m][ko];
            acc0 = mfma_bf16(ah, b0h, acc0);
            acc0 = mfma_bf16(ah, b0l, acc0);
            acc0 = mfma_bf16(al, b0h, acc0);
            acc1 = mfma_bf16(ah, b1h, acc1);
            acc1 = mfma_bf16(ah, b1l, acc1);
            acc1 = mfma_bf16(al, b1h, acc1);
        }
    }

    #pragma unroll
    for (int nt = 0; nt < 2; ++nt) {
        f32x4 a = nt ? acc1 : acc0;
        const int col = c0 + nt*16 + m;
        const float bias = cb[col];
        #pragma unroll
        for (int reg = 0; reg < 4; ++reg) {
            const int row = r0 + w*16 + quad*4 + reg;
            float v = ftanh(a[reg] + bias);
            unsigned short h = f2bf(v);
            unsigned short l = f2bf(v - bf2f(h));
            hvhi[row*1024 + col] = h;
            hvlo[row*1024 + col] = l;
        }
    }
}

// ---------- K2: P[1024][512] = exp2(LOG2E_2*(hv_half @ W2_half + bias)) ----------
// cols 0..255: ea[i,h]=exp2(c*(A+h2b)) (hv cols 0..511, W2 rows 0..511)
// cols 256..511: eb[j,h]=exp2(c*B)     (hv cols 512..1023, W2 rows 512..1023)
// Tile 32x32, grid (16,32)=512 blocks, 256 thr (4 waves, wave=(wm,wn) quadrant).
__global__ __launch_bounds__(256) void k2_mfma(
    const unsigned short* __restrict__ hvhi, const unsigned short* __restrict__ hvlo,
    const unsigned short* __restrict__ w2hi, const unsigned short* __restrict__ w2lo,
    const float* __restrict__ h2b, float* __restrict__ P)
{
    __shared__ unsigned short Ah[32][40], Al[32][40], Bh[32][40], Bl[32][40];
    const int t = threadIdx.x;
    const int r0 = blockIdx.y * 32, c0 = blockIdx.x * 32;
    const int half = (c0 >= 256) ? 1 : 0;
    const int ho = half * 512;
    const int nw = c0 & 255;
    const int w = t >> 6, lane = t & 63;
    const int m = lane & 15, quad = lane >> 4;
    const int wm = (w & 1) * 16, wn = (w >> 1) * 16;

    const int srow = (t & 127) >> 2, sseg = t & 3;  // 128 slots each for A (t<128) / B (t>=128)
    const bool isB = (t >= 128);

    f32x4 acc = {0,0,0,0};

    uint4 ph, pl;
    if (isB) {
        ph = *(const uint4*)(w2hi + (nw+srow)*1024 + ho + sseg*8);
        pl = *(const uint4*)(w2lo + (nw+srow)*1024 + ho + sseg*8);
    } else {
        ph = *(const uint4*)(hvhi + (r0+srow)*1024 + ho + sseg*8);
        pl = *(const uint4*)(hvlo + (r0+srow)*1024 + ho + sseg*8);
    }

    for (int c = 0; c < 16; ++c) {
        __syncthreads();
        if (isB) { *(uint4*)&Bh[srow][sseg*8] = ph; *(uint4*)&Bl[srow][sseg*8] = pl; }
        else     { *(uint4*)&Ah[srow][sseg*8] = ph; *(uint4*)&Al[srow][sseg*8] = pl; }
        __syncthreads();
        if (c + 1 < 16) {
            int k0 = (c+1) * 32;
            if (isB) {
                ph = *(const uint4*)(w2hi + (nw+srow)*1024 + ho + k0 + sseg*8);
                pl = *(const uint4*)(w2lo + (nw+srow)*1024 + ho + k0 + sseg*8);
            } else {
                ph = *(const uint4*)(hvhi + (r0+srow)*1024 + ho + k0 + sseg*8);
                pl = *(const uint4*)(hvlo + (r0+srow)*1024 + ho + k0 + sseg*8);
            }
        }
        #pragma unroll
        for (int ks = 0; ks < 32; ks += 16) {
            const int ko = ks + quad*4;
            s16x4 ah = *(const s16x4*)&Ah[wm + m][ko];
            s16x4 al = *(const s16x4*)&Al[wm + m][ko];
            s16x4 bh = *(const s16x4*)&Bh[wn + m][ko];
            s16x4 bl = *(const s16x4*)&Bl[wn + m][ko];
            acc = mfma_bf16(ah, bh, acc);
            acc = mfma_bf16(ah, bl, acc);
            acc = mfma_bf16(al, bh, acc);
        }
    }

    const int col = c0 + wn + m;
    const float bias = half ? 0.0f : h2b[col];
    #pragma unroll
    for (int reg = 0; reg < 4; ++reg) {
        const int row = r0 + wm + quad*4 + reg;
        P[row*512 + col] = fexp2((acc[reg] + bias) * LOG2E_2);
    }
}

// ---------- K3: score[i,j] = ob + sumw - 2*sum_h w[h]*rcp(1 + ea[i,h]*eb[j,h]) ----------
// exp2(a+b)=exp2(a)*exp2(b): 1 trans + 2 VALU per element. 32x32 tile, grid (32,32), 256 thr.
__global__ __launch_bounds__(256) void k3_pairwise(
    const float* __restrict__ P, const float* __restrict__ w,
    const float* __restrict__ ob, float* __restrict__ out)
{
    __shared__ float As[32][68];   // ea chunk: [i][hh]
    __shared__ float Bs[64][34];   // eb chunk transposed: [hh][j]
    __shared__ float wls[256];
    const int tid = threadIdx.x;
    const int tx = tid & 15;       // cols tx*2..tx*2+1
    const int ty = tid >> 4;       // rows ty*2, ty*2+1
    const int i0 = blockIdx.y * 32, j0 = blockIdx.x * 32;

    wls[tid] = w[tid];

    float acc[2][2] = {};

    for (int h0 = 0; h0 < 256; h0 += 64) {
        __syncthreads();
        #pragma unroll
        for (int it = 0; it < 2; ++it) {
            int idx = tid + it*256;
            int rr  = idx >> 4;
            int c4  = (idx & 15) * 4;
            *(float4*)&As[rr][c4] = *(const float4*)&P[(i0+rr)*512 + h0 + c4];
            float4 bv = *(const float4*)&P[(j0+rr)*512 + 256 + h0 + c4];
            Bs[c4+0][rr] = bv.x;
            Bs[c4+1][rr] = bv.y;
            Bs[c4+2][rr] = bv.z;
            Bs[c4+3][rr] = bv.w;
        }
        __syncthreads();

        for (int hh = 0; hh < 64; hh += 4) {
            float4 wv = *(const float4*)&wls[h0 + hh];
            float4 a0 = *(const float4*)&As[ty*2+0][hh];
            float4 a1 = *(const float4*)&As[ty*2+1][hh];
            float2 b0 = *(const float2*)&Bs[hh+0][tx*2];
            float2 b1 = *(const float2*)&Bs[hh+1][tx*2];
            float2 b2 = *(const float2*)&Bs[hh+2][tx*2];
            float2 b3 = *(const float2*)&Bs[hh+3][tx*2];
            float aa[2][4] = {{a0.x,a0.y,a0.z,a0.w},{a1.x,a1.y,a1.z,a1.w}};
            float bb[4][2] = {{b0.x,b0.y},{b1.x,b1.y},{b2.x,b2.y},{b3.x,b3.y}};
            float ww[4] = {wv.x, wv.y, wv.z, wv.w};
            #pragma unroll
            for (int h = 0; h < 4; ++h)
                #pragma unroll
                for (int r = 0; r < 2; ++r)
                    #pragma unroll
                    for (int q = 0; q < 2; ++q) {
                        float u = fmaf(aa[r][h], bb[h][q], 1.0f);
                        acc[r][q] = fmaf(ww[h], frcp(u), acc[r][q]);
                    }
        }
    }

    float sumw = 0.0f;
    #pragma unroll
    for (int h = 0; h < 256; h += 4) {
        float4 wv = *(const float4*)&wls[h];
        sumw += (wv.x + wv.y) + (wv.z + wv.w);
    }
    const float base = ob[0] + sumw;
    const int row = i0 + ty*2;
    const int col = j0 + tx*2;
    #pragma unroll
    for (int r = 0; r < 2; ++r) {
        float2 o;
        o.x = base - 2.0f*acc[r][0];
        o.y = base - 2.0f*acc[r][1];
        *(float2*)&out[(row+r)*1024 + col] = o;
    }
}

extern "C" void kernel_launch(void* const* d_in, const int* in_sizes, int n_in,
                              void* d_out, int out_size, void* d_ws, size_t ws_size,
                              hipStream_t stream) {
    const float* l0   = (const float*)d_in[0];  // lstms0 [1024,256]
    const float* l1   = (const float*)d_in[1];  // lstms1 [1024,256]
    const float* Wfoh = (const float*)d_in[2];  // [512,512]
    const float* Wfom = (const float*)d_in[3];  // [512,512]
    const float* cb   = (const float*)d_in[4];  // [1024]
    const float* W2   = (const float*)d_in[5];  // [1024,256]
    const float* h2b  = (const float*)d_in[6];  // [256]
    const float* w    = (const float*)d_in[7];  // [256]
    const float* ob   = (const float*)d_in[8];  // [1]
    float* out = (float*)d_out;                 // [1024,1024]

    // ws layout (11 MB total)
    unsigned short* hv_hi  = (unsigned short*)d_ws;          // [1024][1024] bf16
    unsigned short* hv_lo  = hv_hi + 1024*1024;
    float*          P      = (float*)(hv_lo + 1024*1024);    // [1024][512] fp32
    unsigned short* xs_hi  = (unsigned short*)(P + 1024*512);// [1024][512]
    unsigned short* xs_lo  = xs_hi + 1024*512;
    unsigned short* w1t_hi = xs_lo + 1024*512;               // [1024 n][512 k]
    unsigned short* w1t_lo = w1t_hi + 1024*512;
    unsigned short* w2t_hi = w1t_lo + 1024*512;              // [256 n][1024 k]
    unsigned short* w2t_lo = w2t_hi + 256*1024;

    prep_x<<<512, 256, 0, stream>>>(l0, l1, xs_hi, xs_lo);
    prep_wt<<<dim3(16,32), 256, 0, stream>>>(Wfoh, Wfom, 512, 512, 512, w1t_hi, w1t_lo);
    prep_wt<<<dim3(32,8),  256, 0, stream>>>(W2, W2, 1<<30, 256, 1024, w2t_hi, w2t_lo);
    k1_mfma<<<dim3(32,16), 256, 0, stream>>>(xs_hi, xs_lo, w1t_hi, w1t_lo, cb, hv_hi, hv_lo);
    k2_mfma<<<dim3(16,32), 256, 0, stream>>>(hv_hi, hv_lo, w2t_hi, w2t_lo, h2b, P);
    k3_pairwise<<<dim3(32,32), 256, 0, stream>>>(P, w, ob, out);
}

// Round 4
// 130.987 us; speedup vs baseline: 1.4392x; 1.0324x over previous
//
#include <hip/hip_runtime.h>
#include <hip/hip_bf16.h>

typedef short s16x4 __attribute__((ext_vector_type(4)));
typedef short s16x8 __attribute__((ext_vector_type(8)));
typedef float f32x4 __attribute__((ext_vector_type(4)));

#define LOG2E_2 2.8853900817779268f  // 2*log2(e)

__device__ __forceinline__ float fexp2(float x){ return __builtin_amdgcn_exp2f(x); }
__device__ __forceinline__ float frcp (float x){ return __builtin_amdgcn_rcpf(x); }
// tanh(v) = 1 - 2/(1+exp(2v)) = 1 - 2*rcp(1+exp2(LOG2E_2*v))
__device__ __forceinline__ float ftanh(float v){
    return 1.0f - 2.0f * frcp(1.0f + fexp2(LOG2E_2 * v));
}
__device__ __forceinline__ unsigned short f2bf(float v){
    __hip_bfloat16 h = __float2bfloat16(v);
    return __builtin_bit_cast(unsigned short, h);
}
__device__ __forceinline__ float bf2f(unsigned short u){
    return __bfloat162float(__builtin_bit_cast(__hip_bfloat16, u));
}
__device__ __forceinline__ f32x4 mfma32(s16x8 a, s16x8 b, f32x4 c){
    return __builtin_amdgcn_mfma_f32_16x16x32_bf16(a, b, c, 0, 0, 0);
}

// ---------- prep: x = [l0|l1] -> bf16 hi/lo, row-major [1024][512] ----------
__global__ __launch_bounds__(256) void prep_x(
    const float* __restrict__ l0, const float* __restrict__ l1,
    unsigned short* __restrict__ xhi, unsigned short* __restrict__ xlo)
{
    int idx = (blockIdx.x * 256 + threadIdx.x) * 4;   // grid 512 -> covers 512K elems
    int r = idx >> 9, c = idx & 511;
    float4 v = (c < 256) ? *(const float4*)(l0 + r*256 + c)
                         : *(const float4*)(l1 + r*256 + (c - 256));
    ushort4 h, l;
    h.x = f2bf(v.x); l.x = f2bf(v.x - bf2f(h.x));
    h.y = f2bf(v.y); l.y = f2bf(v.y - bf2f(h.y));
    h.z = f2bf(v.z); l.z = f2bf(v.z - bf2f(h.z));
    h.w = f2bf(v.w); l.w = f2bf(v.w - bf2f(h.w));
    *(ushort4*)(xhi + idx) = h;
    *(ushort4*)(xlo + idx) = l;
}

// ---------- prep: transpose+split W[k][n] (fp32) -> Wt_hi/lo[n][k] (bf16) ----------
// src(k,n) = n < splitN ? srcA[k*lda+n] : srcB[k*lda+n-splitN]
__global__ __launch_bounds__(256) void prep_wt(
    const float* __restrict__ srcA, const float* __restrict__ srcB,
    int splitN, int lda, int K,
    unsigned short* __restrict__ dhi, unsigned short* __restrict__ dlo)
{
    __shared__ float F[32][33];
    const int t = threadIdx.x;
    const int k0 = blockIdx.x * 32, n0 = blockIdx.y * 32;
    {
        int kk = t >> 3, n4 = (t & 7) * 4;
        int n = n0 + n4;
        const float* s = (n < splitN) ? (srcA + (k0+kk)*lda + n)
                                      : (srcB + (k0+kk)*lda + (n - splitN));
        float4 v = *(const float4*)s;
        F[kk][n4+0] = v.x; F[kk][n4+1] = v.y; F[kk][n4+2] = v.z; F[kk][n4+3] = v.w;
    }
    __syncthreads();
    {
        int nn = t >> 3, k4 = (t & 7) * 4;
        ushort4 h, l;
        float v0 = F[k4+0][nn]; h.x = f2bf(v0); l.x = f2bf(v0 - bf2f(h.x));
        float v1 = F[k4+1][nn]; h.y = f2bf(v1); l.y = f2bf(v1 - bf2f(h.y));
        float v2 = F[k4+2][nn]; h.z = f2bf(v2); l.z = f2bf(v2 - bf2f(h.z));
        float v3 = F[k4+3][nn]; h.w = f2bf(v3); l.w = f2bf(v3 - bf2f(h.w));
        *(ushort4*)(dhi + (n0+nn)*K + k0 + k4) = h;
        *(ushort4*)(dlo + (n0+nn)*K + k0 + k4) = l;
    }
}

// ---------- K1: hv = tanh(x @ [Wfoh|Wfom] + cb), split-bf16, 16x16x32 MFMA ----------
// M=1024,N=1024,K=512. Tile 64m x 32n, grid (32,16)=512 blocks, 256 thr (4 waves).
// Wave w: m-strip w*16, both 16-col n-tiles. One x32-MFMA per 32-K chunk per tile per term.
__global__ __launch_bounds__(256) void k1_mfma(
    const unsigned short* __restrict__ xhi, const unsigned short* __restrict__ xlo,
    const unsigned short* __restrict__ whi, const unsigned short* __restrict__ wlo,
    const float* __restrict__ cb,
    unsigned short* __restrict__ hvhi, unsigned short* __restrict__ hvlo)
{
    __shared__ unsigned short Ah[64][40], Al[64][40], Bh[32][40], Bl[32][40]; // 80B rows
    const int t = threadIdx.x;
    const int r0 = blockIdx.y * 64, c0 = blockIdx.x * 32;
    const int w = t >> 6, lane = t & 63;
    const int m = lane & 15, quad = lane >> 4;

    const int arow = t >> 2, aseg = t & 3;          // 256 A slots: 64 rows x 4 segs of 8
    const int brow = (t & 127) >> 2, bseg = t & 3;  // 128 B slots (t<128)
    const bool doB = (t < 128);

    f32x4 acc0 = {0,0,0,0}, acc1 = {0,0,0,0};

    const unsigned short* pAh = xhi + (r0+arow)*512 + aseg*8;
    const unsigned short* pAl = xlo + (r0+arow)*512 + aseg*8;
    const unsigned short* pBh = whi + (c0+brow)*512 + bseg*8;
    const unsigned short* pBl = wlo + (c0+brow)*512 + bseg*8;

    uint4 pah = *(const uint4*)pAh;
    uint4 pal = *(const uint4*)pAl;
    uint4 pbh = {}, pbl = {};
    if (doB) { pbh = *(const uint4*)pBh; pbl = *(const uint4*)pBl; }

    for (int c = 0; c < 16; ++c) {
        __syncthreads();
        *(uint4*)&Ah[arow][aseg*8] = pah;
        *(uint4*)&Al[arow][aseg*8] = pal;
        if (doB) {
            *(uint4*)&Bh[brow][bseg*8] = pbh;
            *(uint4*)&Bl[brow][bseg*8] = pbl;
        }
        __syncthreads();
        if (c + 1 < 16) {
            int k0 = (c+1) * 32;
            pah = *(const uint4*)(pAh + k0);
            pal = *(const uint4*)(pAl + k0);
            if (doB) {
                pbh = *(const uint4*)(pBh + k0);
                pbl = *(const uint4*)(pBl + k0);
            }
        }
        {
            const int ko = quad*8;
            s16x8 ah  = *(const s16x8*)&Ah[w*16 + m][ko];
            s16x8 al  = *(const s16x8*)&Al[w*16 + m][ko];
            s16x8 b0h = *(const s16x8*)&Bh[m][ko];
            s16x8 b0l = *(const s16x8*)&Bl[m][ko];
            s16x8 b1h = *(const s16x8*)&Bh[16 + m][ko];
            s16x8 b1l = *(const s16x8*)&Bl[16 + m][ko];
            acc0 = mfma32(ah, b0h, acc0);
            acc0 = mfma32(ah, b0l, acc0);
            acc0 = mfma32(al, b0h, acc0);
            acc1 = mfma32(ah, b1h, acc1);
            acc1 = mfma32(ah, b1l, acc1);
            acc1 = mfma32(al, b1h, acc1);
        }
    }

    #pragma unroll
    for (int nt = 0; nt < 2; ++nt) {
        f32x4 a = nt ? acc1 : acc0;
        const int col = c0 + nt*16 + m;
        const float bias = cb[col];
        #pragma unroll
        for (int reg = 0; reg < 4; ++reg) {
            const int row = r0 + w*16 + quad*4 + reg;
            float v = ftanh(a[reg] + bias);
            unsigned short h = f2bf(v);
            unsigned short l = f2bf(v - bf2f(h));
            hvhi[row*1024 + col] = h;
            hvlo[row*1024 + col] = l;
        }
    }
}

// ---------- K2: P[1024][512] = exp2(LOG2E_2*(hv_half @ W2_half + bias)) ----------
// cols 0..255: ea (hv cols 0..511, W2 rows 0..511); cols 256..511: eb (hv 512.., W2 512..)
// Tile 64m x 32n, grid (16,16)=256 blocks, 256 thr (4 waves), 16x16x32 MFMA.
__global__ __launch_bounds__(256) void k2_mfma(
    const unsigned short* __restrict__ hvhi, const unsigned short* __restrict__ hvlo,
    const unsigned short* __restrict__ w2hi, const unsigned short* __restrict__ w2lo,
    const float* __restrict__ h2b, float* __restrict__ P)
{
    __shared__ unsigned short Ah[64][40], Al[64][40], Bh[32][40], Bl[32][40];
    const int t = threadIdx.x;
    const int r0 = blockIdx.y * 64, c0 = blockIdx.x * 32;
    const int half = (c0 >= 256) ? 1 : 0;
    const int ho = half * 512;
    const int nw = c0 & 255;
    const int w = t >> 6, lane = t & 63;
    const int m = lane & 15, quad = lane >> 4;

    const int arow = t >> 2, aseg = t & 3;
    const int brow = (t & 127) >> 2, bseg = t & 3;
    const bool doB = (t < 128);

    f32x4 acc0 = {0,0,0,0}, acc1 = {0,0,0,0};

    const unsigned short* pAh = hvhi + (r0+arow)*1024 + ho + aseg*8;
    const unsigned short* pAl = hvlo + (r0+arow)*1024 + ho + aseg*8;
    const unsigned short* pBh = w2hi + (nw+brow)*1024 + ho + bseg*8;
    const unsigned short* pBl = w2lo + (nw+brow)*1024 + ho + bseg*8;

    uint4 pah = *(const uint4*)pAh;
    uint4 pal = *(const uint4*)pAl;
    uint4 pbh = {}, pbl = {};
    if (doB) { pbh = *(const uint4*)pBh; pbl = *(const uint4*)pBl; }

    for (int c = 0; c < 16; ++c) {
        __syncthreads();
        *(uint4*)&Ah[arow][aseg*8] = pah;
        *(uint4*)&Al[arow][aseg*8] = pal;
        if (doB) {
            *(uint4*)&Bh[brow][bseg*8] = pbh;
            *(uint4*)&Bl[brow][bseg*8] = pbl;
        }
        __syncthreads();
        if (c + 1 < 16) {
            int k0 = (c+1) * 32;
            pah = *(const uint4*)(pAh + k0);
            pal = *(const uint4*)(pAl + k0);
            if (doB) {
                pbh = *(const uint4*)(pBh + k0);
                pbl = *(const uint4*)(pBl + k0);
            }
        }
        {
            const int ko = quad*8;
            s16x8 ah  = *(const s16x8*)&Ah[w*16 + m][ko];
            s16x8 al  = *(const s16x8*)&Al[w*16 + m][ko];
            s16x8 b0h = *(const s16x8*)&Bh[m][ko];
            s16x8 b0l = *(const s16x8*)&Bl[m][ko];
            s16x8 b1h = *(const s16x8*)&Bh[16 + m][ko];
            s16x8 b1l = *(const s16x8*)&Bl[16 + m][ko];
            acc0 = mfma32(ah, b0h, acc0);
            acc0 = mfma32(ah, b0l, acc0);
            acc0 = mfma32(al, b0h, acc0);
            acc1 = mfma32(ah, b1h, acc1);
            acc1 = mfma32(ah, b1l, acc1);
            acc1 = mfma32(al, b1h, acc1);
        }
    }

    #pragma unroll
    for (int nt = 0; nt < 2; ++nt) {
        f32x4 a = nt ? acc1 : acc0;
        const int col = c0 + nt*16 + m;
        const float bias = half ? 0.0f : h2b[col];
        #pragma unroll
        for (int reg = 0; reg < 4; ++reg) {
            const int row = r0 + w*16 + quad*4 + reg;
            P[row*512 + col] = fexp2((a[reg] + bias) * LOG2E_2);
        }
    }
}

// ---------- K3: score[i,j] = ob + sumw - 2*sum_h w[h]*rcp(1 + ea[i,h]*eb[j,h]) ----------
// 1 trans + 2 VALU per element. 32x32 tile, grid (32,32), 256 thr, reg-prefetch staging.
__global__ __launch_bounds__(256) void k3_pairwise(
    const float* __restrict__ P, const float* __restrict__ w,
    const float* __restrict__ ob, float* __restrict__ out)
{
    __shared__ float As[32][68];   // ea chunk: [i][hh]
    __shared__ float Bs[64][34];   // eb chunk transposed: [hh][j]
    __shared__ float wls[256];
    const int tid = threadIdx.x;
    const int tx = tid & 15;       // cols tx*2..tx*2+1
    const int ty = tid >> 4;       // rows ty*2, ty*2+1
    const int i0 = blockIdx.y * 32, j0 = blockIdx.x * 32;

    wls[tid] = w[tid];

    // staging indices (2 slots per thread)
    int rr0 = tid >> 4,        c40 = (tid & 15) * 4;
    int rr1 = (tid + 256) >> 4, c41 = (tid & 15) * 4;  // rr1 = rr0+16

    float acc[2][2] = {};

    float4 pa0 = *(const float4*)&P[(i0+rr0)*512 + 0 + c40];
    float4 pa1 = *(const float4*)&P[(i0+rr1)*512 + 0 + c41];
    float4 pb0 = *(const float4*)&P[(j0+rr0)*512 + 256 + 0 + c40];
    float4 pb1 = *(const float4*)&P[(j0+rr1)*512 + 256 + 0 + c41];

    for (int c = 0; c < 4; ++c) {
        __syncthreads();
        *(float4*)&As[rr0][c40] = pa0;
        *(float4*)&As[rr1][c41] = pa1;
        Bs[c40+0][rr0] = pb0.x; Bs[c40+1][rr0] = pb0.y;
        Bs[c40+2][rr0] = pb0.z; Bs[c40+3][rr0] = pb0.w;
        Bs[c41+0][rr1] = pb1.x; Bs[c41+1][rr1] = pb1.y;
        Bs[c41+2][rr1] = pb1.z; Bs[c41+3][rr1] = pb1.w;
        __syncthreads();
        if (c + 1 < 4) {
            int h0 = (c+1) * 64;
            pa0 = *(const float4*)&P[(i0+rr0)*512 + h0 + c40];
            pa1 = *(const float4*)&P[(i0+rr1)*512 + h0 + c41];
            pb0 = *(const float4*)&P[(j0+rr0)*512 + 256 + h0 + c40];
            pb1 = *(const float4*)&P[(j0+rr1)*512 + 256 + h0 + c41];
        }

        for (int hh = 0; hh < 64; hh += 4) {
            float4 wv = *(const float4*)&wls[c*64 + hh];
            float4 a0 = *(const float4*)&As[ty*2+0][hh];
            float4 a1 = *(const float4*)&As[ty*2+1][hh];
            float2 b0 = *(const float2*)&Bs[hh+0][tx*2];
            float2 b1 = *(const float2*)&Bs[hh+1][tx*2];
            float2 b2 = *(const float2*)&Bs[hh+2][tx*2];
            float2 b3 = *(const float2*)&Bs[hh+3][tx*2];
            float aa[2][4] = {{a0.x,a0.y,a0.z,a0.w},{a1.x,a1.y,a1.z,a1.w}};
            float bb[4][2] = {{b0.x,b0.y},{b1.x,b1.y},{b2.x,b2.y},{b3.x,b3.y}};
            float ww[4] = {wv.x, wv.y, wv.z, wv.w};
            #pragma unroll
            for (int h = 0; h < 4; ++h)
                #pragma unroll
                for (int r = 0; r < 2; ++r)
                    #pragma unroll
                    for (int q = 0; q < 2; ++q) {
                        float u = fmaf(aa[r][h], bb[h][q], 1.0f);
                        acc[r][q] = fmaf(ww[h], frcp(u), acc[r][q]);
                    }
        }
    }

    float sumw = 0.0f;
    #pragma unroll
    for (int h = 0; h < 256; h += 4) {
        float4 wv = *(const float4*)&wls[h];
        sumw += (wv.x + wv.y) + (wv.z + wv.w);
    }
    const float base = ob[0] + sumw;
    const int row = i0 + ty*2;
    const int col = j0 + tx*2;
    #pragma unroll
    for (int r = 0; r < 2; ++r) {
        float2 o;
        o.x = base - 2.0f*acc[r][0];
        o.y = base - 2.0f*acc[r][1];
        *(float2*)&out[(row+r)*1024 + col] = o;
    }
}

extern "C" void kernel_launch(void* const* d_in, const int* in_sizes, int n_in,
                              void* d_out, int out_size, void* d_ws, size_t ws_size,
                              hipStream_t stream) {
    const float* l0   = (const float*)d_in[0];  // lstms0 [1024,256]
    const float* l1   = (const float*)d_in[1];  // lstms1 [1024,256]
    const float* Wfoh = (const float*)d_in[2];  // [512,512]
    const float* Wfom = (const float*)d_in[3];  // [512,512]
    const float* cb   = (const float*)d_in[4];  // [1024]
    const float* W2   = (const float*)d_in[5];  // [1024,256]
    const float* h2b  = (const float*)d_in[6];  // [256]
    const float* w    = (const float*)d_in[7];  // [256]
    const float* ob   = (const float*)d_in[8];  // [1]
    float* out = (float*)d_out;                 // [1024,1024]

    // ws layout (11 MB total)
    unsigned short* hv_hi  = (unsigned short*)d_ws;          // [1024][1024] bf16
    unsigned short* hv_lo  = hv_hi + 1024*1024;
    float*          P      = (float*)(hv_lo + 1024*1024);    // [1024][512] fp32
    unsigned short* xs_hi  = (unsigned short*)(P + 1024*512);// [1024][512]
    unsigned short* xs_lo  = xs_hi + 1024*512;
    unsigned short* w1t_hi = xs_lo + 1024*512;               // [1024 n][512 k]
    unsigned short* w1t_lo = w1t_hi + 1024*512;
    unsigned short* w2t_hi = w1t_lo + 1024*512;              // [256 n][1024 k]
    unsigned short* w2t_lo = w2t_hi + 256*1024;

    prep_x<<<512, 256, 0, stream>>>(l0, l1, xs_hi, xs_lo);
    prep_wt<<<dim3(16,32), 256, 0, stream>>>(Wfoh, Wfom, 512, 512, 512, w1t_hi, w1t_lo);
    prep_wt<<<dim3(32,8),  256, 0, stream>>>(W2, W2, 1<<30, 256, 1024, w2t_hi, w2t_lo);
    k1_mfma<<<dim3(32,16), 256, 0, stream>>>(xs_hi, xs_lo, w1t_hi, w1t_lo, cb, hv_hi, hv_lo);
    k2_mfma<<<dim3(16,16), 256, 0, stream>>>(hv_hi, hv_lo, w2t_hi, w2t_lo, h2b, P);
    k3_pairwise<<<dim3(32,32), 256, 0, stream>>>(P, w, ob, out);
}